// Round 1
// baseline (550.046 us; speedup 1.0000x reference)
//
#include <hip/hip_runtime.h>

typedef __attribute__((ext_vector_type(8))) __bf16 bf16x8;
typedef __attribute__((ext_vector_type(4))) float f32x4;
typedef unsigned short u16;

#define NEGINF -3.0e38f
#define LOG2E 1.4426950408889634f

__device__ inline f32x4 zero4() { f32x4 v; v[0]=0.f; v[1]=0.f; v[2]=0.f; v[3]=0.f; return v; }

// ---------------------------------------------------------------------------
// GEMM: computes Q = (x @ W_Q^T) * 1/sqrt(512), K = x @ W_K^T, V^T (tiled)
// A = x [16384][512] f32 (converted to bf16 in staging), B = W [512][512] f32.
// Block tile 128x128, BK=32, 256 threads = 4 waves (2x2), wave tile 64x64.
// grid = (12, 128): blockIdx.x: 0-3 -> Q, 4-7 -> K, 8-11 -> V.
// ---------------------------------------------------------------------------
__global__ __launch_bounds__(256, 2)
void gemm_qkv(const float* __restrict__ X, const float* __restrict__ WQ,
              const float* __restrict__ WK, const float* __restrict__ WV,
              u16* __restrict__ Qb, u16* __restrict__ Kb, u16* __restrict__ Vt)
{
    __shared__ u16 As[128*32];
    __shared__ u16 Bs[128*32];
    const int t  = threadIdx.x;
    const int l  = t & 63;
    const int w  = t >> 6;
    const int c  = l & 15;
    const int qd = l >> 4;
    const int m0 = blockIdx.y * 128;
    const int bx = blockIdx.x;
    const int seg = bx >> 2;                    // 0=Q 1=K 2=V
    const float* Wp = (seg == 0) ? WQ : (seg == 1) ? WK : WV;
    const int nw0 = (bx & 3) * 128;             // row offset within W
    const int wm = w >> 1, wn = w & 1;
    const int ar = t >> 2;
    const int ac = (t & 3) * 8;

    f32x4 acc[4][4];
    #pragma unroll
    for (int i = 0; i < 4; i++)
        #pragma unroll
        for (int j = 0; j < 4; j++) acc[i][j] = zero4();

    for (int kk = 0; kk < 512; kk += 32) {
        #pragma unroll
        for (int i = 0; i < 2; ++i) {
            const int r = i*64 + ar;
            const float* ga = &X[(m0 + r)*512 + kk + ac];
            f32x4 a0 = *(const f32x4*)ga;
            f32x4 a1 = *(const f32x4*)(ga + 4);
            bf16x8 va;
            va[0]=(__bf16)a0[0]; va[1]=(__bf16)a0[1]; va[2]=(__bf16)a0[2]; va[3]=(__bf16)a0[3];
            va[4]=(__bf16)a1[0]; va[5]=(__bf16)a1[1]; va[6]=(__bf16)a1[2]; va[7]=(__bf16)a1[3];
            *(bf16x8*)&As[r*32 + ac] = va;
            const float* gb = &Wp[(nw0 + r)*512 + kk + ac];
            f32x4 b0 = *(const f32x4*)gb;
            f32x4 b1 = *(const f32x4*)(gb + 4);
            bf16x8 vb;
            vb[0]=(__bf16)b0[0]; vb[1]=(__bf16)b0[1]; vb[2]=(__bf16)b0[2]; vb[3]=(__bf16)b0[3];
            vb[4]=(__bf16)b1[0]; vb[5]=(__bf16)b1[1]; vb[6]=(__bf16)b1[2]; vb[7]=(__bf16)b1[3];
            *(bf16x8*)&Bs[r*32 + ac] = vb;
        }
        __syncthreads();
        bf16x8 af[4], bfr[4];
        #pragma unroll
        for (int mt = 0; mt < 4; mt++) af[mt]  = *(const bf16x8*)&As[(wm*64 + mt*16 + c)*32 + qd*8];
        #pragma unroll
        for (int nt = 0; nt < 4; nt++) bfr[nt] = *(const bf16x8*)&Bs[(wn*64 + nt*16 + c)*32 + qd*8];
        #pragma unroll
        for (int mt = 0; mt < 4; mt++)
            #pragma unroll
            for (int nt = 0; nt < 4; nt++)
                acc[mt][nt] = __builtin_amdgcn_mfma_f32_16x16x32_bf16(af[mt], bfr[nt], acc[mt][nt], 0, 0, 0);
        __syncthreads();
    }

    const float qscale = 0.044194173824159216f;  // 1/sqrt(512)
    #pragma unroll
    for (int mt = 0; mt < 4; mt++) {
        #pragma unroll
        for (int nt = 0; nt < 4; nt++) {
            #pragma unroll
            for (int r = 0; r < 4; r++) {
                const int gm = m0 + wm*64 + mt*16 + qd*4 + r;   // token row
                const int gn = nw0 + wn*64 + nt*16 + c;         // feature 0..511
                const float v = acc[mt][nt][r];
                if (seg == 0) {
                    *(__bf16*)&Qb[gm*512 + gn] = (__bf16)(v * qscale);
                } else if (seg == 1) {
                    *(__bf16*)&Kb[gm*512 + gn] = (__bf16)v;
                } else {
                    const int bb = gm >> 12;
                    const int ss = gm & 4095;
                    const int kt = ss >> 6;
                    const int kl = ss & 63;
                    // V^T tiled: [b][kt][d=512][kl=64]
                    *(__bf16*)&Vt[((bb*64 + kt)*512 + gn)*64 + kl] = (__bf16)v;
                }
            }
        }
    }
}

// ---------------------------------------------------------------------------
// Flash attention, causal. One block = 64 query rows. 256 threads = 4 waves.
// Wave w: QK rows [16w,16w+16) of the S-tile; PV/O cols [128w,128w+128).
// KV tile = 64 keys. K_lds padded stride 520, V^T_lds padded stride 72,
// P_lds padded stride 72 (all keep 16B alignment, break bank conflicts).
// ---------------------------------------------------------------------------
__global__ __launch_bounds__(256, 1)
void attn_fused(const u16* __restrict__ Qb, const u16* __restrict__ Kb,
                const u16* __restrict__ Vt, float* __restrict__ out)
{
    __shared__ u16 Ks[64*520];    // 66,560 B
    __shared__ u16 Vs[512*72];    // 73,728 B  (V^T: [d][key])
    __shared__ u16 Ps[64*72];     //  9,216 B
    __shared__ float alpha_s[64];
    __shared__ float l_s[64];

    const int t  = threadIdx.x;
    const int l  = t & 63;
    const int w  = t >> 6;
    const int c  = l & 15;
    const int qd = l >> 4;
    const int b  = blockIdx.y;
    const int qt = blockIdx.x;
    const int q0 = qt * 64;

    // Q fragments, resident for whole kernel (A-operand layout: m = c, k = qd*8+j)
    bf16x8 qf[16];
    {
        const int qrow = b*4096 + q0 + w*16 + c;
        #pragma unroll
        for (int ks = 0; ks < 16; ++ks)
            qf[ks] = *(const bf16x8*)&Qb[qrow*512 + ks*32 + qd*8];
    }

    f32x4 o[4][8];
    #pragma unroll
    for (int mt = 0; mt < 4; mt++)
        #pragma unroll
        for (int nt = 0; nt < 8; nt++) o[mt][nt] = zero4();

    float m_r[4] = {NEGINF, NEGINF, NEGINF, NEGINF};
    float l_r[4] = {0.f, 0.f, 0.f, 0.f};

    const int kr = t >> 2;
    const int kc = (t & 3) * 8;

    for (int it = 0; it <= qt; ++it) {
        const int kk0 = it * 64;
        // ---- stage K tile [64][512] -> Ks (padded 520)
        {
            const u16* Kg = &Kb[(b*4096 + kk0 + kr)*512 + kc];
            u16* Kl = &Ks[kr*520 + kc];
            #pragma unroll
            for (int i = 0; i < 16; i++)
                *(bf16x8*)(Kl + 32*i) = *(const bf16x8*)(Kg + 32*i);
        }
        // ---- stage V^T tile [512][64] -> Vs (padded 72)
        {
            const u16* Vg = &Vt[(b*64 + it)*512*64 + t*128];
            #pragma unroll
            for (int i = 0; i < 8; i++)
                *(bf16x8*)&Vs[(2*t)*72 + 8*i]   = *(const bf16x8*)(Vg + 8*i);
            #pragma unroll
            for (int i = 0; i < 8; i++)
                *(bf16x8*)&Vs[(2*t+1)*72 + 8*i] = *(const bf16x8*)(Vg + 64 + 8*i);
        }
        __syncthreads();

        // ---- S = Q K^T for this wave's 16-row strip, 64 key cols
        f32x4 s[4];
        #pragma unroll
        for (int jt = 0; jt < 4; jt++) s[jt] = zero4();
        #pragma unroll
        for (int ks = 0; ks < 16; ++ks) {
            #pragma unroll
            for (int jt = 0; jt < 4; jt++) {
                bf16x8 kf = *(const bf16x8*)&Ks[(jt*16 + c)*520 + ks*32 + qd*8];
                s[jt] = __builtin_amdgcn_mfma_f32_16x16x32_bf16(qf[ks], kf, s[jt], 0, 0, 0);
            }
        }
        if (it == qt) {   // causal mask on diagonal tile (key > query row)
            #pragma unroll
            for (int jt = 0; jt < 4; jt++)
                #pragma unroll
                for (int r = 0; r < 4; r++)
                    if (jt*16 + c > w*16 + qd*4 + r) s[jt][r] = NEGINF;
        }

        // ---- online softmax (4 rows per lane; reduce across 16-lane group)
        #pragma unroll
        for (int r = 0; r < 4; r++) {
            float mx = fmaxf(fmaxf(s[0][r], s[1][r]), fmaxf(s[2][r], s[3][r]));
            #pragma unroll
            for (int off = 1; off < 16; off <<= 1)
                mx = fmaxf(mx, __shfl_xor(mx, off, 16));
            const float mnew = fmaxf(m_r[r], mx);
            const float al = exp2f((m_r[r] - mnew) * LOG2E);
            const float p0 = exp2f((s[0][r] - mnew) * LOG2E);
            const float p1 = exp2f((s[1][r] - mnew) * LOG2E);
            const float p2 = exp2f((s[2][r] - mnew) * LOG2E);
            const float p3 = exp2f((s[3][r] - mnew) * LOG2E);
            float sum = (p0 + p1) + (p2 + p3);
            #pragma unroll
            for (int off = 1; off < 16; off <<= 1)
                sum += __shfl_xor(sum, off, 16);
            l_r[r] = l_r[r] * al + sum;
            m_r[r] = mnew;
            const int row = w*16 + qd*4 + r;
            if (c == 0) alpha_s[row] = al;
            *(__bf16*)&Ps[row*72 +  0 + c] = (__bf16)p0;
            *(__bf16*)&Ps[row*72 + 16 + c] = (__bf16)p1;
            *(__bf16*)&Ps[row*72 + 32 + c] = (__bf16)p2;
            *(__bf16*)&Ps[row*72 + 48 + c] = (__bf16)p3;
        }
        __syncthreads();

        // ---- rescale O by alpha (rows of this lane's accumulator)
        #pragma unroll
        for (int mt = 0; mt < 4; mt++) {
            const float a0 = alpha_s[mt*16 + qd*4 + 0];
            const float a1 = alpha_s[mt*16 + qd*4 + 1];
            const float a2 = alpha_s[mt*16 + qd*4 + 2];
            const float a3 = alpha_s[mt*16 + qd*4 + 3];
            #pragma unroll
            for (int nt = 0; nt < 8; nt++) {
                o[mt][nt][0] *= a0; o[mt][nt][1] *= a1;
                o[mt][nt][2] *= a2; o[mt][nt][3] *= a3;
            }
        }
        // ---- O += P * V  (this wave: d cols 128w..128w+128)
        #pragma unroll
        for (int ks2 = 0; ks2 < 2; ++ks2) {
            bf16x8 pa[4];
            #pragma unroll
            for (int mt = 0; mt < 4; mt++)
                pa[mt] = *(const bf16x8*)&Ps[(mt*16 + c)*72 + ks2*32 + qd*8];
            #pragma unroll
            for (int nt = 0; nt < 8; nt++) {
                bf16x8 vb = *(const bf16x8*)&Vs[(w*128 + nt*16 + c)*72 + ks2*32 + qd*8];
                #pragma unroll
                for (int mt = 0; mt < 4; mt++)
                    o[mt][nt] = __builtin_amdgcn_mfma_f32_16x16x32_bf16(pa[mt], vb, o[mt][nt], 0, 0, 0);
            }
        }
        __syncthreads();
    }

    // ---- final normalize and store
    {
        const int row = w*16 + qd*4;
        if (c == 0) {
            l_s[row+0] = l_r[0]; l_s[row+1] = l_r[1];
            l_s[row+2] = l_r[2]; l_s[row+3] = l_r[3];
        }
    }
    __syncthreads();
    #pragma unroll
    for (int mt = 0; mt < 4; mt++) {
        const float i0 = 1.0f / l_s[mt*16 + qd*4 + 0];
        const float i1 = 1.0f / l_s[mt*16 + qd*4 + 1];
        const float i2 = 1.0f / l_s[mt*16 + qd*4 + 2];
        const float i3 = 1.0f / l_s[mt*16 + qd*4 + 3];
        #pragma unroll
        for (int nt = 0; nt < 8; nt++) {
            float* op = &out[(b*4096 + q0 + mt*16 + qd*4)*512 + w*128 + nt*16 + c];
            op[0]    = o[mt][nt][0] * i0;
            op[512]  = o[mt][nt][1] * i1;
            op[1024] = o[mt][nt][2] * i2;
            op[1536] = o[mt][nt][3] * i3;
        }
    }
}

extern "C" void kernel_launch(void* const* d_in, const int* in_sizes, int n_in,
                              void* d_out, int out_size, void* d_ws, size_t ws_size,
                              hipStream_t stream)
{
    (void)in_sizes; (void)n_in; (void)out_size; (void)ws_size;
    const float* X  = (const float*)d_in[0];
    const float* WQ = (const float*)d_in[1];
    const float* WK = (const float*)d_in[2];
    const float* WV = (const float*)d_in[3];
    float* out = (float*)d_out;
    char* ws = (char*)d_ws;
    u16* Qb = (u16*)(ws);                                  // 16 MB bf16 [16384][512], pre-scaled
    u16* Kb = (u16*)(ws + (size_t)16*1024*1024);           // 16 MB bf16 [16384][512]
    u16* Vt = (u16*)(ws + (size_t)32*1024*1024);           // 16 MB bf16 V^T tiled [4][64][512][64]

    gemm_qkv<<<dim3(12, 128), 256, 0, stream>>>(X, WQ, WK, WV, Qb, Kb, Vt);
    attn_fused<<<dim3(64, 4), 256, 0, stream>>>(Qb, Kb, Vt, out);
}